// Round 7
// baseline (107.483 us; speedup 1.0000x reference)
//
#include <hip/hip_runtime.h>
#include <hip/hip_bf16.h>

// B=8192 rows, N=64 nodes, C=256. Per node: MLP 1->C->C->1 on s=Q*Y,
// then softmax over [z0, z_1..z_64] per row. Output f32 [B, 65].
//
// Round 7: BARRIER-FREE main loop.
//  - A (=H1) never touches LDS: each lane computes its MFMA A-fragment
//    in registers from s[row] (4 regs) + w1/b1 k-window (broadcast LDS read).
//  - W2 stays in registers (breg[4][8] = 128 VGPR/wave).
//  - cross-wave z reduction deferred: per-tile partials -> zAll LDS (16KB),
//    ONE __syncthreads at kernel end, then a final sum+store pass.
//  - asm memory clobber per tile prevents LICM of the loop-invariant
//    w1/b1 LDS reads into 128 registers (R2 spill trap).

#define BM 64
#define CHUNK 1024
#define NTILES 16

typedef __attribute__((ext_vector_type(8))) short bf16x8;
typedef __attribute__((ext_vector_type(4))) float f32x4;
typedef __attribute__((ext_vector_type(4))) unsigned int u32x4;

__device__ __forceinline__ unsigned short f2bf(float f) {
    unsigned int u = __float_as_uint(f);
    u += 0x7FFFu + ((u >> 16) & 1u);   // RNE
    return (unsigned short)(u >> 16);
}

// dst.lo = bf16(a), dst.hi = bf16(b) — single HW instruction
__device__ __forceinline__ unsigned int cvtpk(float a, float b) {
    unsigned int r;
    asm("v_cvt_pk_bf16_f32 %0, %1, %2" : "=v"(r) : "v"(a), "v"(b));
    return r;
}

// sum across the 16 lanes of each DPP row
__device__ __forceinline__ float row_reduce16(float x) {
    int v;
    v = __builtin_amdgcn_update_dpp(0, __float_as_int(x), 0xB1, 0xF, 0xF, false);  // quad_perm [1,0,3,2]
    x += __int_as_float(v);
    v = __builtin_amdgcn_update_dpp(0, __float_as_int(x), 0x4E, 0xF, 0xF, false);  // quad_perm [2,3,0,1]
    x += __int_as_float(v);
    v = __builtin_amdgcn_update_dpp(0, __float_as_int(x), 0x124, 0xF, 0xF, false); // row_ror:4
    x += __int_as_float(v);
    v = __builtin_amdgcn_update_dpp(0, __float_as_int(x), 0x128, 0xF, 0xF, false); // row_ror:8
    x += __int_as_float(v);
    return x;
}

// ---------------------------------------------------------------------------
// Kernel 0: W2 [N][C][D] f32 -> W2t [N][D][C] bf16 (K-contiguous for MFMA B).
// ---------------------------------------------------------------------------
__global__ __launch_bounds__(256) void transpose_w2(
    const float* __restrict__ W2, unsigned short* __restrict__ W2t)
{
    __shared__ float tile[32][33];
    const int n  = blockIdx.z;
    const int c0 = blockIdx.y << 5;
    const int d0 = blockIdx.x << 5;
    const int tx = threadIdx.x & 31;
    const int ty = threadIdx.x >> 5;
    const float* src = W2 + ((size_t)n << 16);
    #pragma unroll
    for (int j = 0; j < 32; j += 8)
        tile[ty + j][tx] = src[(size_t)(c0 + ty + j) * 256 + d0 + tx];
    __syncthreads();
    unsigned short* dst = W2t + ((size_t)n << 16);
    #pragma unroll
    for (int j = 0; j < 32; j += 8)
        dst[(size_t)(d0 + ty + j) * 256 + c0 + tx] = f2bf(tile[tx][ty + j]);
}

// ---------------------------------------------------------------------------
// Kernel 0b: S[n][b] = Q[b][n]*Y[b][n]  (node-major, 64x64 LDS transpose)
// ---------------------------------------------------------------------------
__global__ __launch_bounds__(256) void make_s(
    const float* __restrict__ Q, const float* __restrict__ Y,
    float* __restrict__ S)
{
    __shared__ float ts[64][65];
    const int b0 = blockIdx.x << 6;
    #pragma unroll
    for (int jj = 0; jj < 16; jj++) {
        int idx = threadIdx.x + (jj << 8);
        int r = idx >> 6, c = idx & 63;
        ts[r][c] = Q[(size_t)(b0 + r) * 64 + c] * Y[(size_t)(b0 + r) * 64 + c];
    }
    __syncthreads();
    #pragma unroll
    for (int jj = 0; jj < 16; jj++) {
        int idx = threadIdx.x + (jj << 8);
        int nn = idx >> 6, bb = idx & 63;
        S[((size_t)nn << 13) + b0 + bb] = ts[bb][nn];
    }
}

// ---------------------------------------------------------------------------
// Kernel 1: W2-resident, A-in-register fused MLP GEMM.
// grid (64 nodes, 8 chunks), 256 thr = 4 waves; wave wc owns 64 rows x 64 cols.
// NO barriers in the 16-tile main loop.
// ---------------------------------------------------------------------------
__global__ __launch_bounds__(256, 2) void gemm_node(
    const float* __restrict__ S,
    const float* __restrict__ W1, const float* __restrict__ b1,
    const unsigned short* __restrict__ W2t,
    const float* __restrict__ b2, const float* __restrict__ W3,
    const float* __restrict__ b3, float* __restrict__ Z)
{
    __shared__ float s_lds[CHUNK];            // 4 KB
    __shared__ float w1_lds[256];             // 1 KB
    __shared__ float b1_lds[256];             // 1 KB
    __shared__ float zAll[NTILES][4][BM];     // 16 KB

    const int tid  = threadIdx.x;
    const int lane = tid & 63;
    const int wc   = tid >> 6;            // 0..3 : col quarter (64 cols)
    const int l15  = lane & 15;
    const int g8   = (lane >> 4) << 3;    // k sub-offset within 32-slice
    const int n    = blockIdx.x;
    const int cr0  = blockIdx.y * CHUNK;

    const float* W1n = W1 + n * 256;
    const float* b1n = b1 + n * 256;
    const unsigned short* W2n = W2t + ((size_t)n << 16);
    const float* Sn = S + ((size_t)n << 13);
    float* Zn = Z + ((size_t)n << 13);

    // ---- prologue fills ----
    {
        float4 v = *reinterpret_cast<const float4*>(Sn + cr0 + (tid << 2));
        *reinterpret_cast<float4*>(&s_lds[tid << 2]) = v;
    }
    if (tid < 64)
        reinterpret_cast<float4*>(w1_lds)[tid] =
            reinterpret_cast<const float4*>(W1n)[tid];
    else if (tid < 128)
        reinterpret_cast<float4*>(b1_lds)[tid - 64] =
            reinterpret_cast<const float4*>(b1n)[tid - 64];

    // ---- B fragments: wave's 64-col slice of W2[n] in regs (128 VGPR) ----
    bf16x8 breg[4][8];
    #pragma unroll
    for (int p = 0; p < 4; p++)
        #pragma unroll
        for (int ks = 0; ks < 8; ks++) {
            int col = (wc << 6) + (p << 4) + l15;
            int k   = (ks << 5) + g8;
            breg[p][ks] = *reinterpret_cast<const bf16x8*>(&W2n[(size_t)col * 256 + k]);
        }

    // ---- hoisted epilogue constants ----
    float w3v[4], b2v[4];
    #pragma unroll
    for (int p = 0; p < 4; p++) {
        int d = (wc << 6) + (p << 4) + l15;
        w3v[p] = W3[n * 256 + d];
        b2v[p] = b2[n * 256 + d];
    }
    const float b3n = b3[n];

    __syncthreads();   // s_lds / w1_lds / b1_lds ready — LAST barrier until end

    for (int t = 0; t < NTILES; t++) {
        // keep LDS loads inside the loop (block LICM -> register explosion)
        asm volatile("" ::: "memory");

        // s values for this tile's 4 row-groups (row = m*16 + l15)
        float sv[4];
        #pragma unroll
        for (int m = 0; m < 4; m++)
            sv[m] = s_lds[(t << 6) + (m << 4) + l15];

        f32x4 acc[4][4] = {};

        #pragma unroll
        for (int ks = 0; ks < 8; ks++) {
            const int kb = (ks << 5) + g8;
            // broadcast reads: 4 distinct 16B addrs per read across the wave
            float4 wA = *reinterpret_cast<const float4*>(&w1_lds[kb]);
            float4 wB = *reinterpret_cast<const float4*>(&w1_lds[kb + 4]);
            float4 bA = *reinterpret_cast<const float4*>(&b1_lds[kb]);
            float4 bB = *reinterpret_cast<const float4*>(&b1_lds[kb + 4]);
            // build A fragments in registers: h1 = relu(s*w1 + b1)
            bf16x8 afr[4];
            #pragma unroll
            for (int m = 0; m < 4; m++) {
                const float s0 = sv[m];
                union { u32x4 u; bf16x8 s; } cv;
                cv.u[0] = cvtpk(fmaxf(fmaf(s0, wA.x, bA.x), 0.f),
                                fmaxf(fmaf(s0, wA.y, bA.y), 0.f));
                cv.u[1] = cvtpk(fmaxf(fmaf(s0, wA.z, bA.z), 0.f),
                                fmaxf(fmaf(s0, wA.w, bA.w), 0.f));
                cv.u[2] = cvtpk(fmaxf(fmaf(s0, wB.x, bB.x), 0.f),
                                fmaxf(fmaf(s0, wB.y, bB.y), 0.f));
                cv.u[3] = cvtpk(fmaxf(fmaf(s0, wB.z, bB.z), 0.f),
                                fmaxf(fmaf(s0, wB.w, bB.w), 0.f));
                afr[m] = cv.s;
            }
            __builtin_amdgcn_s_setprio(1);
            #pragma unroll
            for (int m = 0; m < 4; m++)
                #pragma unroll
                for (int p = 0; p < 4; p++)
                    acc[m][p] = __builtin_amdgcn_mfma_f32_16x16x32_bf16(
                        afr[m], breg[p][ks], acc[m][p], 0, 0, 0);
            __builtin_amdgcn_s_setprio(0);
        }

        // ---- per-tile partial epilogue: pz = sum_d relu(acc + b2) * w3 ----
        #pragma unroll
        for (int m = 0; m < 4; m++) {
            f32x4 pzv = {0.f, 0.f, 0.f, 0.f};
            #pragma unroll
            for (int p = 0; p < 4; p++)
                #pragma unroll
                for (int j = 0; j < 4; j++)
                    pzv[j] = fmaf(fmaxf(acc[m][p][j] + b2v[p], 0.f), w3v[p], pzv[j]);
            #pragma unroll
            for (int j = 0; j < 4; j++) pzv[j] = row_reduce16(pzv[j]);
            if (l15 == 0)
                *reinterpret_cast<f32x4*>(
                    &zAll[t][wc][(m << 4) + ((lane >> 4) << 2)]) = pzv;
        }
        // no barrier: waves write disjoint zAll[.][wc][.] slices
    }

    __syncthreads();   // all zAll partials visible

    // ---- final: z = b3 + sum_wc zAll, coalesced node-major store ----
    #pragma unroll
    for (int q = 0; q < 4; q++) {
        int idx = tid + (q << 8);
        int t   = idx >> 6;
        int row = idx & 63;
        float z = b3n + zAll[t][0][row] + zAll[t][1][row]
                      + zAll[t][2][row] + zAll[t][3][row];
        Zn[cr0 + (t << 6) + row] = z;
    }
}

// ---------------------------------------------------------------------------
// Kernel 2: per-row 65-way softmax. One wave per batch row (lane = node).
// Z node-major: Z[n][b].
// ---------------------------------------------------------------------------
__global__ __launch_bounds__(256) void softmax_rows(
    const float* __restrict__ Q, const float* __restrict__ Y,
    const float* __restrict__ Z, const float* __restrict__ bias0,
    float* __restrict__ out)
{
    const int lane = threadIdx.x & 63;
    const int wv   = threadIdx.x >> 6;
    const int b    = (blockIdx.x << 2) + wv;

    float s = Q[(size_t)b * 64 + lane] * Y[(size_t)b * 64 + lane];
    float ssum = s;
    #pragma unroll
    for (int mask = 32; mask >= 1; mask >>= 1) ssum += __shfl_xor(ssum, mask, 64);
    const float z0 = bias0[0] - ssum;

    float zl = Z[((size_t)lane << 13) + b];
    float mx = zl;
    #pragma unroll
    for (int mask = 32; mask >= 1; mask >>= 1) mx = fmaxf(mx, __shfl_xor(mx, mask, 64));
    mx = fmaxf(mx, z0);

    float el = expf(zl - mx);
    float e0 = expf(z0 - mx);
    float den = el;
    #pragma unroll
    for (int mask = 32; mask >= 1; mask >>= 1) den += __shfl_xor(den, mask, 64);
    den += e0;
    const float inv = 1.0f / den;

    out[(size_t)b * 65 + 1 + lane] = el * inv;
    if (lane == 0) out[(size_t)b * 65] = e0 * inv;
}

// ---------------------------------------------------------------------------
extern "C" void kernel_launch(void* const* d_in, const int* in_sizes, int n_in,
                              void* d_out, int out_size, void* d_ws, size_t ws_size,
                              hipStream_t stream)
{
    const float* Q     = (const float*)d_in[0];
    const float* Y     = (const float*)d_in[1];
    const float* W1    = (const float*)d_in[2];
    const float* b1    = (const float*)d_in[3];
    const float* W2    = (const float*)d_in[4];
    const float* b2    = (const float*)d_in[5];
    const float* W3    = (const float*)d_in[6];
    const float* b3    = (const float*)d_in[7];
    const float* bias0 = (const float*)d_in[8];
    float* out = (float*)d_out;

    // ws: W2t bf16 8.39MB | Z f32 node-major 2.10MB | S f32 node-major 2.10MB
    unsigned short* W2t = (unsigned short*)d_ws;
    float* Z = (float*)((char*)d_ws + (size_t)8388608);
    float* S = (float*)((char*)d_ws + (size_t)8388608 + 2097152);

    transpose_w2<<<dim3(8, 8, 64), 256, 0, stream>>>(W2, W2t);
    make_s<<<128, 256, 0, stream>>>(Q, Y, S);
    gemm_node<<<dim3(64, 8), 256, 0, stream>>>(S, W1, b1, W2t, b2, W3, b3, Z);
    softmax_rows<<<2048, 256, 0, stream>>>(Q, Y, Z, bias0, out);
}